// Round 1
// baseline (6695.294 us; speedup 1.0000x reference)
//
#include <hip/hip_runtime.h>
#include <hip/hip_bf16.h>

typedef unsigned short u16;
typedef unsigned int u32;
typedef __attribute__((ext_vector_type(8))) short short8;
typedef __attribute__((ext_vector_type(8))) u16 ushort8;
typedef __attribute__((ext_vector_type(4))) float f32x4;

__device__ __forceinline__ float bf2f(u16 x){ u32 u=((u32)x)<<16; return __builtin_bit_cast(float,u); }
__device__ __forceinline__ u16 f2bf(float f){ u32 u=__builtin_bit_cast(u32,f); u32 r=(u+0x7fffu+((u>>16)&1u))>>16; return (u16)r; }
__device__ __forceinline__ float sigf(float x){ return 1.f/(1.f+__expf(-x)); }

// ---------------- prologue kernels ----------------

__global__ __launch_bounds__(256) void k_cast(const float* __restrict__ s, u16* __restrict__ d, long n){
  long i = ((long)blockIdx.x*256 + threadIdx.x)*8;
  if (i >= n) return;
  float4 a = *(const float4*)(s+i);
  float4 b = *(const float4*)(s+i+4);
  ushort8 o;
  o[0]=f2bf(a.x); o[1]=f2bf(a.y); o[2]=f2bf(a.z); o[3]=f2bf(a.w);
  o[4]=f2bf(b.x); o[5]=f2bf(b.y); o[6]=f2bf(b.z); o[7]=f2bf(b.w);
  *(ushort8*)(d+i) = o;
}

// WC[j][0:2816] = [W_ih[j][0:1792] | W_hh[j][0:1024]]  (bf16)
__global__ __launch_bounds__(256) void k_build_wc(const float* __restrict__ Wih, const float* __restrict__ Whh,
                                                  u16* __restrict__ WC){
  long i8 = (long)blockIdx.x*256 + threadIdx.x;           // 4096*352
  if (i8 >= (long)4096*352) return;
  int j = (int)(i8/352); int kk = (int)(i8%352)*8;
  const float* src = (kk < 1792) ? (Wih + (long)j*1792 + kk) : (Whh + (long)j*1024 + (kk-1792));
  u16* dst = WC + (long)j*2816 + kk;
  ushort8 o;
  #pragma unroll
  for (int q=0;q<8;++q) o[q] = f2bf(src[q]);
  *(ushort8*)dst = o;
}

// W_attT[m][k] = W_att[k][m]  (bf16)
__global__ __launch_bounds__(256) void k_wattT(const float* __restrict__ Wa, u16* __restrict__ WT){
  int id = blockIdx.x*256 + threadIdx.x;                  // 1M
  int m = id >> 10, k = id & 1023;
  WT[(long)m*1024 + k] = f2bf(Wa[(long)k*1024 + m]);
}

// mean over S (full S, unmasked, matches reference)
__global__ __launch_bounds__(1024) void k_mean(const u16* __restrict__ ENC, float* __restrict__ mean){
  int b = blockIdx.x, h = threadIdx.x;
  const u16* p = ENC + ((long)b<<20) + h;
  float s = 0.f;
  for (int ss=0; ss<1024; ++ss) s += bf2f(p[(long)ss<<10]);
  mean[b*1024 + h] = s * (1.f/1024.f);
}

// h0 = tanh(mean @ W_init^T + b_init) -> XC[0] h-slot (offset 1792)
__global__ __launch_bounds__(256) void k_h0(const float* __restrict__ mean, const float* __restrict__ Wi,
                                            const float* __restrict__ bi, u16* __restrict__ XC0){
  int n = blockIdx.x*16 + (threadIdx.x & 15);
  int bq = threadIdx.x >> 4;
  const float* wr = Wi + (long)n*1024;
  for (int r=0;r<4;++r){
    int b = bq*4 + r;
    const float* mr = mean + b*1024;
    float s = 0.f;
    for (int k=0;k<1024;++k) s += mr[k]*wr[k];
    XC0[(long)b*2816 + 1792 + n] = f2bf(tanhf(s + bi[n]));
  }
}

// a_e / t_e slots of XC for all t  (zeros where !prev_valid)
__global__ __launch_bounds__(256) void k_embed(const float* __restrict__ pemb, const float* __restrict__ temb,
      const int* __restrict__ pid, const int* __restrict__ tid_, const int* __restrict__ slen,
      u16* __restrict__ XC){
  int t = blockIdx.x >> 6, b = blockIdx.x & 63;
  bool valid = (t>0) && (t < slen[b]);
  int pi = pid[b*64 + t], ti = tid_[b*64 + t];
  u16* dst = XC + (long)blockIdx.x*2816;
  for (int kk = threadIdx.x; kk < 768; kk += 256){
    float v = 0.f;
    if (valid) v = (kk<512) ? pemb[(long)pi*512 + kk] : temb[(long)ti*256 + (kk-512)];
    dst[(kk<512) ? kk : (1024+kk)] = f2bf(v);
  }
}

// ---------------- per-step kernels ----------------

// gates GEMM (M=64, K=2816) + LSTM pointwise fused via shfl; 256 blocks x 256 thr
// block covers n in [4*bx,4*bx+4) for all 4 gates; wave w = M-tile (16 b rows)
__global__ __launch_bounds__(256) void k_lstm(const u16* __restrict__ XCt, u16* __restrict__ XCn,
      const u16* __restrict__ WC, const float* __restrict__ bih, const float* __restrict__ bhh,
      float* __restrict__ cst, u16* __restrict__ HC){
  int l = threadIdx.x & 63, w = threadIdx.x >> 6;
  int c = l & 15, g = l >> 4;
  int n0 = blockIdx.x << 2;
  int j = n0 + (c & 3) + ((c >> 2) << 10);                 // weight row (gate interleave)
  const u16* ap = XCt + (long)(w*16 + c)*2816 + g*8;
  const u16* bp = WC  + (long)j*2816 + g*8;
  f32x4 acc = {0.f,0.f,0.f,0.f};
  #pragma unroll 8
  for (int kb=0; kb<88; ++kb){
    short8 av = *(const short8*)(ap + kb*32);
    short8 bv = *(const short8*)(bp + kb*32);
    acc = __builtin_amdgcn_mfma_f32_16x16x32_bf16(av, bv, acc, 0, 0, 0);
  }
  float biasj = bih[j] + bhh[j];
  int lbase = l & 0x33;                                    // keep (l>>4) group + low2 of col
  #pragma unroll
  for (int r=0;r<4;++r){
    float val = acc[r] + biasj;
    float iv = __shfl(val, lbase);
    float fv = __shfl(val, lbase+4);
    float gv = __shfl(val, lbase+8);
    float ov = __shfl(val, lbase+12);
    if ((l & 12) == 0){
      int b = w*16 + g*4 + r;
      int n = n0 + (l & 3);
      float cold = cst[b*1024 + n];
      float cn = sigf(fv)*cold + sigf(iv)*tanhf(gv);
      float hn = sigf(ov)*tanhf(cn);
      cst[b*1024 + n] = cn;
      u16 hb = f2bf(hn);
      XCn[(long)b*2816 + 1792 + n] = hb;
      HC[b*2048 + n] = hb;
    }
  }
}

// generic small-M GEMM: out = A[M x K] @ W[N x K]^T   (block: 64 rows x 16 cols, 4 waves)
// MODE 0: f32 store   1: tanh->bf16 dual store   2: tanh(+bias)->bf16   3: +bias -> f32
template<int MODE>
__global__ __launch_bounds__(256) void k_gemm(const u16* __restrict__ A, long lda,
      const u16* __restrict__ W, int K, const float* __restrict__ bias,
      float* __restrict__ OF, long ldo, u16* __restrict__ OB1, long ldb1,
      u16* __restrict__ OB2, long ldb2){
  int l = threadIdx.x & 63, w = threadIdx.x >> 6;
  int c = l & 15, g = l >> 4;
  int n0 = blockIdx.x*16, m0 = blockIdx.y*64;
  const u16* ap = A + (long)(m0 + w*16 + c)*lda + g*8;
  const u16* bp = W + (long)(n0 + c)*K + g*8;
  f32x4 acc = {0.f,0.f,0.f,0.f};
  int kit = K >> 5;
  #pragma unroll 4
  for (int kb=0; kb<kit; ++kb){
    short8 av = *(const short8*)(ap + kb*32);
    short8 bv = *(const short8*)(bp + kb*32);
    acc = __builtin_amdgcn_mfma_f32_16x16x32_bf16(av, bv, acc, 0, 0, 0);
  }
  #pragma unroll
  for (int r=0;r<4;++r){
    int row = m0 + w*16 + g*4 + r;
    int col = n0 + c;
    float v = acc[r];
    if (MODE==0){ OF[(long)row*ldo + col] = v; }
    if (MODE==1){ u16 x = f2bf(tanhf(v)); OB1[(long)row*ldb1 + col] = x; OB2[(long)row*ldb2 + col] = x; }
    if (MODE==2){ OB1[(long)row*ldb1 + col] = f2bf(tanhf(v + bias[col])); }
    if (MODE==3){ OF[(long)row*ldo + col] = v + bias[col]; }
  }
}

// attention: online softmax + ctx, 4 blocks per b (s-chunks), partials out
__global__ __launch_bounds__(256) void k_attn(const u16* __restrict__ ENC, const float* __restrict__ hW,
      const int* __restrict__ slen, float* __restrict__ pm, float* __restrict__ pl,
      float* __restrict__ ctxp){
  int b = blockIdx.x >> 2, p = blockIdx.x & 3;
  int l = threadIdx.x & 63, w = threadIdx.x >> 6;
  int len = slen[b]; if (len < 1) len = 1; if (len > 1024) len = 1024;
  int chunk = (len + 3) >> 2;
  int s0 = p*chunk, s1 = s0 + chunk; if (s1 > len) s1 = len;
  float hw[16], ctx[16];
  const float* hwp = hW + b*1024 + l*16;
  #pragma unroll
  for (int jj=0;jj<16;++jj){ hw[jj]=hwp[jj]; ctx[jj]=0.f; }
  float m = -INFINITY, lsum = 0.f;
  for (int s = s0 + w; s < s1; s += 4){
    const u16* ep = ENC + (((long)(b*1024 + s))<<10) + l*16;
    uint4 q0 = *(const uint4*)ep;
    uint4 q1 = *(const uint4*)(ep + 8);
    float e[16];
    e[0]=bf2f((u16)(q0.x&0xffff)); e[1]=bf2f((u16)(q0.x>>16));
    e[2]=bf2f((u16)(q0.y&0xffff)); e[3]=bf2f((u16)(q0.y>>16));
    e[4]=bf2f((u16)(q0.z&0xffff)); e[5]=bf2f((u16)(q0.z>>16));
    e[6]=bf2f((u16)(q0.w&0xffff)); e[7]=bf2f((u16)(q0.w>>16));
    e[8]=bf2f((u16)(q1.x&0xffff)); e[9]=bf2f((u16)(q1.x>>16));
    e[10]=bf2f((u16)(q1.y&0xffff)); e[11]=bf2f((u16)(q1.y>>16));
    e[12]=bf2f((u16)(q1.z&0xffff)); e[13]=bf2f((u16)(q1.z>>16));
    e[14]=bf2f((u16)(q1.w&0xffff)); e[15]=bf2f((u16)(q1.w>>16));
    float sc = 0.f;
    #pragma unroll
    for (int jj=0;jj<16;++jj) sc += e[jj]*hw[jj];
    #pragma unroll
    for (int off=32; off; off>>=1) sc += __shfl_xor(sc, off);
    float nm = fmaxf(m, sc);
    float pe = __expf(sc - nm);
    if (nm > m){
      float corr = __expf(m - nm);
      lsum *= corr;
      #pragma unroll
      for (int jj=0;jj<16;++jj) ctx[jj] *= corr;
      m = nm;
    }
    lsum += pe;
    #pragma unroll
    for (int jj=0;jj<16;++jj) ctx[jj] += pe*e[jj];
  }
  __shared__ float s_ctx[4][1024];
  __shared__ float s_m[4], s_l[4];
  #pragma unroll
  for (int jj=0;jj<16;++jj) s_ctx[w][l*16+jj] = ctx[jj];
  if (l == 0){ s_m[w] = m; s_l[w] = lsum; }
  __syncthreads();
  float M4 = fmaxf(fmaxf(s_m[0],s_m[1]), fmaxf(s_m[2],s_m[3]));
  float wei[4]; float L = 0.f;
  #pragma unroll
  for (int q=0;q<4;++q){ wei[q] = (s_m[q] == -INFINITY) ? 0.f : __expf(s_m[q]-M4); L += wei[q]*s_l[q]; }
  int t = threadIdx.x;
  long base = (long)blockIdx.x*1024;
  for (int mm = t*4; mm < t*4+4; ++mm){
    ctxp[base + mm] = wei[0]*s_ctx[0][mm] + wei[1]*s_ctx[1][mm] + wei[2]*s_ctx[2][mm] + wei[3]*s_ctx[3][mm];
  }
  if (t == 0){ pm[blockIdx.x] = M4; pl[blockIdx.x] = L; }
}

// combine 4 partials per b -> ctx (bf16) into HC ctx-slot
__global__ __launch_bounds__(256) void k_combine(const float* __restrict__ pm, const float* __restrict__ pl,
      const float* __restrict__ ctxp, u16* __restrict__ HC){
  int b = blockIdx.x, t = threadIdx.x;
  float m0=pm[b*4], m1=pm[b*4+1], m2=pm[b*4+2], m3=pm[b*4+3];
  float M = fmaxf(fmaxf(m0,m1), fmaxf(m2,m3));
  float w0 = (m0==-INFINITY)?0.f:__expf(m0-M);
  float w1 = (m1==-INFINITY)?0.f:__expf(m1-M);
  float w2 = (m2==-INFINITY)?0.f:__expf(m2-M);
  float w3 = (m3==-INFINITY)?0.f:__expf(m3-M);
  float L = w0*pl[b*4] + w1*pl[b*4+1] + w2*pl[b*4+2] + w3*pl[b*4+3];
  float inv = (L > 0.f) ? 1.f/L : 0.f;
  const float* c0 = ctxp + (long)(b*4+0)*1024;
  const float* c1 = ctxp + (long)(b*4+1)*1024;
  const float* c2 = ctxp + (long)(b*4+2)*1024;
  const float* c3 = ctxp + (long)(b*4+3)*1024;
  for (int mm = t*4; mm < t*4+4; ++mm){
    float v = (w0*c0[mm] + w1*c1[mm] + w2*c2[mm] + w3*c3[mm]) * inv;
    HC[b*2048 + 1024 + mm] = f2bf(v);
  }
}

// ---------------- epilogue ----------------
// per-b deterministic loss accumulation (no atomics)
__global__ __launch_bounds__(256) void k_loss(const float* __restrict__ LG, const int* __restrict__ tgt,
      const int* __restrict__ slen, float* __restrict__ out){
  int b = blockIdx.x;
  int w = threadIdx.x >> 6, l = threadIdx.x & 63;
  int len = slen[b];
  float accum = 0.f;
  for (int t = w; t < 64; t += 4){
    if (t >= len) continue;
    const float* lp = LG + ((long)(t*64 + b))*256;
    float v0=lp[l], v1=lp[l+64], v2=lp[l+128], v3=lp[l+192];
    float mx = fmaxf(fmaxf(v0,v1), fmaxf(v2,v3));
    #pragma unroll
    for (int off=32; off; off>>=1) mx = fmaxf(mx, __shfl_xor(mx, off));
    float s = __expf(v0-mx)+__expf(v1-mx)+__expf(v2-mx)+__expf(v3-mx);
    #pragma unroll
    for (int off=32; off; off>>=1) s += __shfl_xor(s, off);
    float ltg = lp[tgt[b*64 + t]];
    float p = __expf(ltg - mx)/s;
    accum += logf(p + 1e-8f);
  }
  __shared__ float sm[4];
  if (l == 0) sm[w] = accum;
  __syncthreads();
  if (threadIdx.x == 0) out[b] = sm[0]+sm[1]+sm[2]+sm[3];
}

extern "C" void kernel_launch(void* const* d_in, const int* in_sizes, int n_in,
                              void* d_out, int out_size, void* d_ws, size_t ws_size,
                              hipStream_t stream){
  const float* enc      = (const float*)d_in[0];
  const float* W_ih     = (const float*)d_in[1];
  const float* b_ih     = (const float*)d_in[2];
  const float* W_hh     = (const float*)d_in[3];
  const float* b_hh     = (const float*)d_in[4];
  const float* W_att    = (const float*)d_in[5];
  const float* W_attvec = (const float*)d_in[6];
  const float* W_init   = (const float*)d_in[7];
  const float* b_init   = (const float*)d_in[8];
  const float* W_q2a    = (const float*)d_in[9];
  const float* b_q2a    = (const float*)d_in[10];
  const float* prod_emb = (const float*)d_in[11];
  const float* prod_bias= (const float*)d_in[12];
  const float* type_emb = (const float*)d_in[13];
  const int* prev_pid   = (const int*)d_in[14];
  const int* prev_tid   = (const int*)d_in[15];
  const int* target     = (const int*)d_in[16];
  const int* sk_lens    = (const int*)d_in[17];
  const int* src_lens   = (const int*)d_in[18];
  float* out = (float*)d_out;

  char* ws = (char*)d_ws;
  size_t o = 0;
  auto alloc = [&](size_t bytes)->char*{ char* p = ws + o; o += (bytes + 255) & ~(size_t)255; return p; };
  u16*  ENC  = (u16*)alloc((size_t)64*1024*1024*2);   // 128MB
  u16*  WC   = (u16*)alloc((size_t)4096*2816*2);      // 22.5MB
  u16*  WAVT = (u16*)alloc((size_t)1024*1024*2);
  u16*  WAVEC= (u16*)alloc((size_t)1024*2048*2);
  u16*  WQ   = (u16*)alloc((size_t)512*1024*2);
  u16*  PE   = (u16*)alloc((size_t)256*512*2);
  u16*  XC   = (u16*)alloc((size_t)65*64*2816*2);     // 23.4MB
  u16*  HC   = (u16*)alloc((size_t)64*2048*2);
  u16*  ATT  = (u16*)alloc((size_t)64*64*1024*2);     // 8MB
  float* HW  = (float*)alloc((size_t)64*1024*4);
  float* CST = (float*)alloc((size_t)64*1024*4);
  float* MEAN= (float*)alloc((size_t)64*1024*4);
  float* PM  = (float*)alloc(256*4);
  float* PL  = (float*)alloc(256*4);
  float* CTXP= (float*)alloc((size_t)256*1024*4);
  u16*  Q    = (u16*)alloc((size_t)4096*512*2);
  float* LG  = (float*)alloc((size_t)4096*256*4);
  (void)ws_size; (void)in_sizes; (void)n_in; (void)out_size;  // requires ws >= ~208MB

  hipMemsetAsync(XC, 0, (size_t)64*2816*2, stream);   // XC[0] (a_e/att/t_e zero; h filled by k_h0)
  hipMemsetAsync(CST, 0, (size_t)64*1024*4, stream);  // c0 = 0

  k_cast<<<32768,256,0,stream>>>(enc, ENC, (long)64*1024*1024);
  k_cast<<<1024,256,0,stream>>>(W_attvec, WAVEC, (long)1024*2048);
  k_cast<<<256,256,0,stream>>>(W_q2a, WQ, (long)512*1024);
  k_cast<<<64,256,0,stream>>>(prod_emb, PE, (long)256*512);
  k_build_wc<<<5632,256,0,stream>>>(W_ih, W_hh, WC);
  k_wattT<<<4096,256,0,stream>>>(W_att, WAVT);
  k_mean<<<64,1024,0,stream>>>(ENC, MEAN);
  k_h0<<<64,256,0,stream>>>(MEAN, W_init, b_init, XC);
  k_embed<<<4096,256,0,stream>>>(prod_emb, type_emb, prev_pid, prev_tid, sk_lens, XC);

  for (int t=0; t<64; ++t){
    u16* XCt = XC + (size_t)t*64*2816;
    u16* XCn = XC + (size_t)(t+1)*64*2816;
    k_lstm<<<256,256,0,stream>>>(XCt, XCn, WC, b_ih, b_hh, CST, HC);
    k_gemm<0><<<dim3(64,1),256,0,stream>>>(HC, 2048L, WAVT, 1024, nullptr,
                                           HW, 1024L, nullptr, 0L, nullptr, 0L);
    k_attn<<<256,256,0,stream>>>(ENC, HW, src_lens, PM, PL, CTXP);
    k_combine<<<64,256,0,stream>>>(PM, PL, CTXP, HC);
    k_gemm<1><<<dim3(64,1),256,0,stream>>>(HC, 2048L, WAVEC, 2048, nullptr,
                                           nullptr, 0L, XCn + 512, 2816L,
                                           ATT + (size_t)t*64*1024, 1024L);
  }

  k_gemm<2><<<dim3(32,64),256,0,stream>>>(ATT, 1024L, WQ, 1024, b_q2a,
                                          nullptr, 0L, Q, 512L, nullptr, 0L);
  k_gemm<3><<<dim3(16,64),256,0,stream>>>(Q, 512L, PE, 512, prod_bias,
                                          LG, 256L, nullptr, 0L, nullptr, 0L);
  k_loss<<<64,256,0,stream>>>(LG, target, sk_lens, out);
}